// Round 10
// baseline (3147.596 us; speedup 1.0000x reference)
//
#include <hip/hip_runtime.h>

// samx_qkv_1bit R21: two ROWS per block — amortize the handshake.
// R20 post-mortem: LDS flag polls cost more than s_barrier (1531->1633);
// reverted to the R19 skeleton. Landscape: legs have slack (R18/R19), the
// serialized segment resists additions (R17), the handshake resists
// replacement (R20). ~400-600cy/step is fixed handshake cost.
// R21: each 128-thread block owns TWO independent rows. wave0 = key side of
// both, wave1 = query side of both, sharing the same two barriers:
//   [p1(r0),p1(r1) || q(r0),q(r1)]  A  [p2(r0),p2(r1)] drain B
// Barrier+drain paid once per TWO row-steps; row latencies overlap. To make
// overlap real despite data-dependent walks, latency-critical loads batch
// across rows in straight-line code: wave1 issues both rows' spec-hop load
// sets before resolving either; wave0's p1 = stage1 (ballots/readlane/
// recd-issue/permute-issue x2) + stage2 (recd-dependent clone x2).
// Rows fully independent (separate arrays; coupling = barrier timing only)
// -> per-row logic is R19's verified code with a row index.
// LDS 2x40960 = 81920B -> exactly 2 blocks/CU; 512 blocks = 2x256
// co-resident. gfx950 allows >64KB/workgroup (AITER fmha: 160KB).

#define NSTATES 4096
#define TLEN 2048

typedef unsigned long long u64m;

__device__ __forceinline__ int f_tr(u64m r, int s) {   // transition by symbol
  return (int)(short)(unsigned short)(r >> (s << 4));
}
__device__ __forceinline__ int f_fl(u64m r) {          // suffix link
  return (int)(short)(unsigned short)(r >> 32);
}
__device__ __forceinline__ int f_ml(u64m r) {          // max length
  return (int)(r >> 48);
}

// img[lane-1] without DS: DPP row_shr:1 + patch row-boundary lanes 16/32/48.
__device__ __forceinline__ int lane_shr1(int v, int lane) {
  int sh = __builtin_amdgcn_update_dpp(0, v, 0x111 /*row_shr:1*/, 0xF, 0xF, true);
  const int v15 = __builtin_amdgcn_readlane(v, 15);
  const int v31 = __builtin_amdgcn_readlane(v, 31);
  const int v47 = __builtin_amdgcn_readlane(v, 47);
  if (lane == 16) sh = v15;
  if (lane == 32) sh = v31;
  if (lane == 48) sh = v47;
  return sh;
}

__global__ __launch_bounds__(128)
void samx_main(const float* __restrict__ q,
               const float* __restrict__ k,
               unsigned* __restrict__ outpos,
               int T, int C) {
  __shared__ u64m           reca[2][NSTATES];  // tr0|tr1|fl|ml (16b each)
  __shared__ unsigned short rla[2][NSTATES];   // last end pos, 0xFFFF = -1

  unsigned short* recwv[2] = {(unsigned short*)&reca[0][0],
                              (unsigned short*)&reca[1][0]};
  unsigned*       rechv[2] = {(unsigned*)&reca[0][0],
                              (unsigned*)&reca[1][0]};

  const int lane = threadIdx.x & 63;
  const int wid = threadIdx.x >> 6;   // 0 = key wave, 1 = query wave

  for (int s = threadIdx.x; s < NSTATES; s += 128) {
    reca[0][s] = 0x0000FFFFFFFFFFFFull;
    reca[1][s] = 0x0000FFFFFFFFFFFFull;
    rla[0][s] = 0xFFFFu;
    rla[1][s] = 0xFFFFu;
  }

  size_t rowbase[2];
  unsigned* outr[2];
  unsigned bits[2] = {0u, 0u};
  {
    const float* srcb = (wid == 0) ? k : q;
#pragma unroll
    for (int r = 0; r < 2; ++r) {
      const int row = blockIdx.x * 2 + r;
      const int b = row / C;
      const int c = row - b * C;
      rowbase[r] = (size_t)b * (size_t)T * (size_t)C + (size_t)c;
      outr[r] = outpos + rowbase[r];
      const float* src = srcb + rowbase[r];
      const int t0 = lane * 32;
#pragma unroll 8
      for (int jj = 0; jj < 32; ++jj) {
        if (src[(size_t)(t0 + jj) * C] > 0.0f) bits[r] |= (1u << jj);
      }
    }
  }
  __syncthreads();

  // ---- wave0 per-row state ----
  int  cid[2]  = {0, 0};
  bool cval[2] = {lane == 0, lane == 0};
  bool trunc[2] = {false, false};
  int  g[2] = {0, 0}, mlg[2] = {0, 0}, uu[2] = {1, 1};
  u64m pf_rec[2] = {reca[0][0], reca[1][0]};
  // ---- wave1 per-row state ----
  int  w[2] = {0, 0}, h[2] = {0, 0};
  u64m rrP[2] = {reca[0][0], reca[1][0]};

  int symv[2];
#pragma unroll
  for (int r = 0; r < 2; ++r)
    symv[r] = (int)(__builtin_amdgcn_readlane((int)bits[r], 0) & 1);

  for (int i = 0; i < T; ++i) {
    bool hot[2]; int jj[2], mljv[2];
#pragma unroll
    for (int r = 0; r < 2; ++r) {
      hot[r] = !trunc[r];
      jj[r] = uu[r]++;          // wave1's copies unused
      mljv[r] = mlg[r] + 1;
    }

    // phase1 -> phase2 carriers (wave0)
    int d[2] = {-1, -1}, bb[2] = {-1, -1}, flj[2] = {0, 0};
    int ndd[2] = {0, 0}, newlen[2] = {2, 2}, pushed[2] = {0, 0};
    int t2v[2] = {64, 64}, mlp[2] = {0, 0}, imgv[2] = {-1, -1};
    bool prefl[2] = {false, false}, inrun[2] = {false, false};
    bool nobrk[2] = {false, false};
    u64m recd[2] = {0, 0};

    if (wid == 0) {
      // ===== P1 stage1: ballots + recd/permute ISSUE for both rows =======
#pragma unroll
      for (int r = 0; r < 2; ++r) if (hot[r]) {
        const int ks = symv[r];
        const u64m rk = pf_rec[r];                 // prefetched gather
        imgv[r] = f_tr(rk, ks);
        const int myml = f_ml(rk);
        const u64m brkmask = __ballot(cval[r] && imgv[r] != -1);
        nobrk[r] = (brkmask == 0);
        t2v[r] = nobrk[r] ? 64 : (int)__builtin_ctzll(brkmask);
        const int t2c = (t2v[r] > 63) ? 63 : t2v[r];
        d[r] = __builtin_amdgcn_readlane(imgv[r], t2c);
        mlp[r] = __builtin_amdgcn_readlane(myml, t2c);
        prefl[r] = cval[r] && (lane < t2v[r]);

        recd[r] = reca[r][d[r] < 0 ? 0 : d[r]];    // load issued

        // permute machinery (img-only)
        const int previmg = lane_shr1(imgv[r], lane);
        const bool rs = cval[r] && lane >= t2v[r] &&
                        (lane == t2v[r] || imgv[r] != previmg);
        const u64m rsmask = __ballot(rs);
        ndd[r] = (int)__builtin_popcountll(rsmask);
        newlen[r] = ndd[r] + 2;  // [j] + ndd images + [root]
        const unsigned below =
            __builtin_amdgcn_mbcnt_hi((unsigned)(rsmask >> 32),
                __builtin_amdgcn_mbcnt_lo((unsigned)rsmask, 0u));
        const int dst = rs ? ((int)below + 1) : 0; // trash -> slot 0
        pushed[r] = __builtin_amdgcn_ds_permute(dst << 2, imgv[r]);
      }
      // ===== P1 stage2: recd-dependent clone work for both rows ==========
#pragma unroll
      for (int r = 0; r < 2; ++r) if (hot[r]) {
        const int ks = symv[r];
        int dtr0 = f_tr(recd[r], 0);
        int dtr1 = f_tr(recd[r], 1);
        const unsigned fmdhi = (unsigned)(recd[r] >> 32);  // fl|ml of d
        if (!nobrk[r]) {
          const int mld = (int)(fmdhi >> 16);
          if (mlp[r] + 1 == mld) {
            flj[r] = d[r];
          } else {
            bb[r] = uu[r]++;  // clone of d with length mlp+1
            // patch deferred prefix-store effect on tk[d]
            const u64m pb = __ballot(prefl[r] && cid[r] == d[r]);
            if (pb != 0ull) { if (ks) dtr1 = jj[r]; else dtr0 = jj[r]; }
            if (lane == 0) {
              // rl[bb] elided: bb is slot 1 of new chain -> stamped i
              reca[r][bb[r]] = (u64m)(unsigned short)dtr0
                             | ((u64m)(unsigned short)dtr1 << 16)
                             | ((u64m)(fmdhi & 0xFFFFu) << 32)
                             | ((u64m)(unsigned)(mlp[r] + 1) << 48);
            }
            flj[r] = bb[r];
          }
        }
        if (lane == 0)
          rechv[r][2 * jj[r] + 1] =
              (unsigned)(flj[r] & 0xFFFF) | ((unsigned)mljv[r] << 16);

        if (bb[r] >= 0) {  // redirect run: contiguous img==d from t2
          const u64m eq = __ballot(cval[r] && imgv[r] == d[r]) >> t2v[r];
          const int runlen = (eq == ~0ull) ? 64 : (int)__builtin_ctzll(~eq);
          inrun[r] = cval[r] && lane >= t2v[r] && lane < t2v[r] + runlen;
        }
      }
    } else {
      // ===== QUERY: spec-hop loads batched for both rows =================
      u64m fresh[2], rr2[2]; int rl2[2], tvs[2];
#pragma unroll
      for (int r = 0; r < 2; ++r) {
        const int qs = symv[r];
        fresh[r] = reca[r][w[r]];            // authoritative reca[w]
        tvs[r] = f_tr(rrP[r], qs);           // spec from cached rec
        const int ps = (tvs[r] != -1) ? tvs[r] : 0;
        rr2[r] = reca[r][ps];                // spec hop-2 record
        rl2[r] = (int)(short)rla[r][ps];     // spec hop-2 rla
      }
#pragma unroll
      for (int r = 0; r < 2; ++r) {
        const int qs = symv[r];
        int p, x;
        u64m recP; int rlv;
        if (fresh[r] == rrP[r] && tvs[r] != -1) {
          p = tvs[r]; x = h[r] + 1; recP = rr2[r]; rlv = rl2[r];
        } else {
          // generic walk1 from the fresh (authoritative) record
          u64m rr = fresh[r]; p = w[r]; x = h[r];
          for (;;) {
            const int tv = f_tr(rr, qs);
            if (tv != -1) { p = tv; x = x + 1; break; }
            const int mp = f_ml(rr);
            if (x > mp) x = mp;
            p = f_fl(rr);
            if (p == -1) { p = 0; x = 0; break; }
            rr = reca[r][p];
          }
          recP = reca[r][p]; rlv = (int)(short)rla[r][p];
        }

        unsigned fmv = (unsigned)(recP >> 32);
        int vst = p;
        for (;;) {
          const int fv = (int)(short)(fmv & 0xFFFFu);
          if (fv == -1) break;
          const unsigned fmf = rechv[r][2 * fv + 1];
          const int rlf = (int)(short)rla[r][fv];
          if ((int)(fmf >> 16) < x) break;
          vst = fv; fmv = fmf; rlv = rlf;
        }
        int rv = -1;
        for (;;) {
          if (vst == -1) { rv = -1; break; }
          if ((int)(fmv >> 16) > 0 && rlv >= 0) { rv = rlv; break; }
          vst = (int)(short)(fmv & 0xFFFFu);
          if (vst == -1) { rv = -1; break; }
          fmv = rechv[r][2 * vst + 1];
          rlv = (int)(short)rla[r][vst];
        }
        w[r] = p; h[r] = x;
        rrP[r] = recP;
        if (lane == 0) outr[r][(size_t)i * C] = (unsigned)(rv + 1);
      }
    }

    asm volatile("" ::: "memory");
    __builtin_amdgcn_s_barrier();   // ---- A: query reads done (both rows) --
    asm volatile("" ::: "memory");

    if (wid == 0) {
      // ============ P2 — visible stores, both rows ======================
#pragma unroll
      for (int r = 0; r < 2; ++r) {
        const int ks = symv[r];
        if (hot[r]) {
          if (prefl[r]) recwv[r][4 * cid[r] + ks] = (unsigned short)jj[r];
          if (inrun[r]) recwv[r][4 * cid[r] + ks] = (unsigned short)bb[r];
          if (bb[r] >= 0 && lane == 0)
            recwv[r][4 * d[r] + 2] = (unsigned short)bb[r];  // fl[d]=bb

          // new chain: [j, flj, run-start images #1.., root]
          int nv = 0;
          if (lane == 0) nv = jj[r];
          else if (lane == 1) nv = flj[r];
          else if (lane - 1 < ndd[r]) nv = pushed[r];
          const bool nval = (lane < newlen[r]);
          if (nval) rla[r][nv] = (unsigned short)i;

          const bool overflow = (newlen[r] > 64);
          if (overflow) {  // cold: stamp the unstored tail serially
            const int nv63 = __builtin_amdgcn_readlane(nv, 63);
            if (lane == 0) {
              int vp = (int)(short)(rechv[r][2 * nv63 + 1] & 0xFFFFu);
              while (vp != -1) {
                rla[r][vp] = (unsigned short)i;
                vp = (int)(short)(rechv[r][2 * vp + 1] & 0xFFFFu);
              }
            }
          }
          cid[r] = nv; cval[r] = nval; trunc[r] = overflow;
        } else {
          // ===== COLD fallback: reference-exact serial step ==============
          int pcur = g[r], d2 = -1, idbrk = -1;
          for (;;) {
            if (pcur == -1) break;
            const u64m rr = reca[r][pcur];
            const int tv = f_tr(rr, ks);
            if (tv != -1) { d2 = tv; idbrk = pcur; break; }
            if (lane == 0) recwv[r][4 * pcur + ks] = (unsigned short)jj[r];
            pcur = f_fl(rr);
          }
          int fl2 = 0;
          if (d2 != -1) {
            const int mlp2 = f_ml(reca[r][idbrk]);
            const u64m rd2 = reca[r][d2];
            const int mld = f_ml(rd2);
            if (mlp2 + 1 == mld) {
              fl2 = d2;
            } else {
              const int bbc = uu[r]++;
              const int drl = (int)(short)rla[r][d2];
              if (lane == 0) {
                reca[r][bbc] = (u64m)(unsigned short)f_tr(rd2, 0)
                             | ((u64m)(unsigned short)f_tr(rd2, 1) << 16)
                             | ((u64m)((unsigned)(rd2 >> 32) & 0xFFFFu) << 32)
                             | ((u64m)(unsigned)(mlp2 + 1) << 48);
                rla[r][bbc] = (unsigned short)drl;
                recwv[r][4 * d2 + 2] = (unsigned short)bbc;   // fl[d2]=bbc
              }
              fl2 = bbc;
              int p3 = idbrk;
              for (;;) {
                if (p3 == -1) break;
                const u64m r3 = reca[r][p3];
                const int tv3 = f_tr(r3, ks);
                if (tv3 != d2) break;
                if (lane == 0) recwv[r][4 * p3 + ks] = (unsigned short)bbc;
                p3 = f_fl(r3);
              }
            }
          }
          if (lane == 0)
            rechv[r][2 * jj[r] + 1] =
                (unsigned)(fl2 & 0xFFFF) | ((unsigned)mljv[r] << 16);
          // full propagation walk; rebuild lane chain while stamping
          int vp = jj[r], ncs = 0;
          bool tr2 = false;
          for (;;) {
            if (vp == -1) break;
            if (ncs < 64) { if (lane == ncs) cid[r] = vp; ++ncs; }
            else tr2 = true;
            if (lane == 0) rla[r][vp] = (unsigned short)i;
            vp = (int)(short)(rechv[r][2 * vp + 1] & 0xFFFFu);
          }
          cval[r] = (lane < ncs);
          trunc[r] = tr2;
        }
        g[r] = jj[r]; mlg[r] = mljv[r];
      }
    }
    // wave1: nothing in phase2.

    // next-step symbols (both waves, own streams)
    if (i + 1 < T) {
      const int in = i + 1;
#pragma unroll
      for (int r = 0; r < 2; ++r) {
        const unsigned bw =
            (unsigned)__builtin_amdgcn_readlane((int)bits[r], in >> 5);
        symv[r] = (int)((bw >> (in & 31)) & 1u);
      }
    }

    // drain wave0's LDS stores; raw barrier (wave1's outr stays in flight)
    asm volatile("s_waitcnt lgkmcnt(0)" ::: "memory");
    if (wid == 0 && i + 1 < T) {
      // gather prefetches: post-drain (in-order DS => see all step-i stores)
      pf_rec[0] = reca[0][cid[0]];
      pf_rec[1] = reca[1][cid[1]];
    }
    __builtin_amdgcn_s_barrier();   // ---- B: post-i published (both rows) --
    asm volatile("" ::: "memory");
  }
}

// Fully parallel epilogue: vidx (u32, = r+1, 0 = no match) -> sign*e.
__global__ __launch_bounds__(256)
void samx_epilogue(const float* __restrict__ v,
                   const float* __restrict__ e,
                   unsigned* __restrict__ out,
                   int T, int C, int total) {
  const int idx = blockIdx.x * 256 + threadIdx.x;
  if (idx >= total) return;
  const unsigned vidx = out[idx];
  const int c = idx % C;
  const int bi = idx / C;
  const int b = bi / T;
  const float ev = e[c];
  float val = -ev;  // y=0
  if (vidx != 0u) {
    if (v[((size_t)b * (size_t)T + (size_t)vidx) * (size_t)C + (size_t)c] > 0.0f)
      val = ev;
  }
  out[idx] = __float_as_uint(val);
}

extern "C" void kernel_launch(void* const* d_in, const int* in_sizes, int n_in,
                              void* d_out, int out_size, void* d_ws, size_t ws_size,
                              hipStream_t stream) {
  const float* q = (const float*)d_in[0];
  const float* k = (const float*)d_in[1];
  const float* v = (const float*)d_in[2];
  const float* e = (const float*)d_in[3];

  const int C = in_sizes[3];
  const int T = TLEN;
  const int B = in_sizes[0] / (T * C);
  const int total = out_size;

  samx_main<<<dim3((B * C) / 2), dim3(128), 0, stream>>>(
      q, k, (unsigned*)d_out, T, C);
  samx_epilogue<<<dim3((total + 255) / 256), dim3(256), 0, stream>>>(
      v, e, (unsigned*)d_out, T, C, total);
}

// Round 11
// 1582.139 us; speedup vs baseline: 1.9895x; 1.9895x over previous
//
#include <hip/hip_runtime.h>

// samx_qkv_1bit R22: revert to R19 — the verified optimum of this design.
// R21 post-mortem: 2 rows/block (81920B LDS) halved occupancy to 1 wave/SIMD
// (23->12%) -> 2x regression. Constraint recorded: <=40KB LDS/block
// (4 blocks/CU, 2 waves/SIMD) is mandatory; two automata can't fit.
// Landscape now closed: legs have slack (R18 -16us, R19 ~0), serialized
// segment rejects additions (R17 +330), handshake rejects polling (R20
// +100), amortization rejects the occupancy trade (R21 +1570). The
// dependence cycle query(i) -> p2(i) -> query(i+1) makes 2 syncs/step
// irreducible for the two-agent split.
// Structure (R16/R18/R19, all harness-verified, absmax 0):
//   128 threads: wave0 = key side, wave1 = query side, same 40KB automaton.
//   Phase1 [B->A]: wave0 key reads + fresh-state stores (j/bb unreachable
//     by the query until phase2 links them); wave1 full query + outr.
//   Phase2 [A->B]: wave0 query-visible stores; lgkmcnt(0) drain; barrier.
//   wave1 spec first-hop: cached rrP=reca[w] verified against a fresh load;
//     spec hop-2 loads issued in parallel (2 serial hops -> 1). Mismatch
//     redoes walk1 from the authoritative record (reference-exact).
//   wave0 gather prefetch: reca[cid] issued post-drain pre-barrier-B;
//     latency hides under barrier wake + wave1's next query.
// Cold fallback (chain > 64) R10-verified verbatim in wave0's phase2.

#define NSTATES 4096
#define TLEN 2048

typedef unsigned long long u64m;

__device__ __forceinline__ int f_tr(u64m r, int s) {   // transition by symbol
  return (int)(short)(unsigned short)(r >> (s << 4));
}
__device__ __forceinline__ int f_fl(u64m r) {          // suffix link
  return (int)(short)(unsigned short)(r >> 32);
}
__device__ __forceinline__ int f_ml(u64m r) {          // max length
  return (int)(r >> 48);
}

// img[lane-1] without DS: DPP row_shr:1 + patch row-boundary lanes 16/32/48.
// Lane 0 result is don't-care (rs requires lane >= t2 >= 1).
__device__ __forceinline__ int lane_shr1(int v, int lane) {
  int sh = __builtin_amdgcn_update_dpp(0, v, 0x111 /*row_shr:1*/, 0xF, 0xF, true);
  const int v15 = __builtin_amdgcn_readlane(v, 15);
  const int v31 = __builtin_amdgcn_readlane(v, 31);
  const int v47 = __builtin_amdgcn_readlane(v, 47);
  if (lane == 16) sh = v15;
  if (lane == 32) sh = v31;
  if (lane == 48) sh = v47;
  return sh;
}

__global__ __launch_bounds__(128)
void samx_main(const float* __restrict__ q,
               const float* __restrict__ k,
               unsigned* __restrict__ outpos,
               int T, int C) {
  __shared__ u64m           reca[NSTATES];  // tr0[15:0] tr1[31:16] fl[47:32] ml[63:48]
  __shared__ unsigned short rla[NSTATES];   // last end pos, 0xFFFF = -1

  unsigned short* recw = (unsigned short*)reca;  // [4*s + f]: f=0 tr0,1 tr1,2 fl,3 ml
  unsigned*       rech = (unsigned*)reca;        // [2*s+1] = fl|ml<<16

  const int row = blockIdx.x;
  const int b = row / C;
  const int c = row - b * C;
  const int lane = threadIdx.x & 63;
  const int wid = threadIdx.x >> 6;   // 0 = key wave, 1 = query wave

  for (int s = threadIdx.x; s < NSTATES; s += 128) {
    reca[s] = 0x0000FFFFFFFFFFFFull;  // tr0=tr1=fl=-1, ml=0
    rla[s] = 0xFFFFu;
  }

  const size_t rowbase = (size_t)b * (size_t)T * (size_t)C + (size_t)c;
  unsigned* outr = outpos + rowbase;

  // Binarize only the stream this wave consumes: wave0 -> k, wave1 -> q.
  // Lane L holds bits t = 32L..32L+31.
  const float* src = (wid == 0 ? k : q) + rowbase;
  unsigned bits = 0u;
  {
    const int t0 = lane * 32;
#pragma unroll 8
    for (int jj = 0; jj < 32; ++jj) {
      if (src[(size_t)(t0 + jj) * C] > 0.0f) bits |= (1u << jj);
    }
  }
  __syncthreads();

  // ---- wave0 state ----
  int cid = 0;                  // my chain slot's state id (slot = lane)
  bool cval = (lane == 0);      // slot validity (valid slots contiguous)
  bool trunc = false;
  int g = 0;    // last state (uniform; used by fallback)
  int mlg = 0;  // ml[g]
  int u = 1;    // next free state id
  u64m pf_rec = reca[0];   // wave0: prefetched reca[cid]
  // ---- wave1 state ----
  int w = 0;    // query-match state
  int h = 0;    // query-match length
  u64m rrP = reca[0];  // wave1: reca[w] as read during the previous query
                       // (possibly stale wrt the last p2 - verified each use)

  int sym = (int)(__builtin_amdgcn_readlane((int)bits, 0) & 1);  // ks / qs

  for (int i = 0; i < T; ++i) {
    const bool hot = !trunc;
    const int j = u++;          // wave1's copies of u/j are unused
    const int mlj = mlg + 1;

    // phase1 -> phase2 carriers (wave0)
    int d = -1, bb = -1, flj = 0, ndd = 0, newlen = 2, pushed = 0;
    bool prefl = false, inrun = false;

    if (wid == 0) {
      // ================= PHASE 1 — KEY (reads + fresh stores) =============
      if (hot) {
        const int ks = sym;
        const u64m rk = pf_rec;                    // prefetched gather
        const int img = f_tr(rk, ks);
        const int myml = f_ml(rk);
        const u64m brkmask = __ballot(cval && img != -1);
        const bool nobrk = (brkmask == 0);
        const int t2 = nobrk ? 64 : (int)__builtin_ctzll(brkmask);
        const int t2c = (t2 > 63) ? 63 : t2;
        d = __builtin_amdgcn_readlane(img, t2c);
        const int mlp = __builtin_amdgcn_readlane(myml, t2c);
        prefl = cval && (lane < t2);

        const u64m recd = reca[d < 0 ? 0 : d];     // ONE b64 for d

        // permute machinery (img-only; overlaps recd load)
        const int previmg = lane_shr1(img, lane);
        const bool rs = cval && lane >= t2 && (lane == t2 || img != previmg);
        const u64m rsmask = __ballot(rs);
        ndd = (int)__builtin_popcountll(rsmask);
        newlen = ndd + 2;  // [j] + ndd images + [root]
        const unsigned below =
            __builtin_amdgcn_mbcnt_hi((unsigned)(rsmask >> 32),
                __builtin_amdgcn_mbcnt_lo((unsigned)rsmask, 0u));
        const int dst = rs ? ((int)below + 1) : 0; // trash -> slot 0
        pushed = __builtin_amdgcn_ds_permute(dst << 2, img);

        // clone decision + fresh-state stores (invisible to wave1: nothing
        // links to j/bb until phase2)
        int dtr0 = f_tr(recd, 0);
        int dtr1 = f_tr(recd, 1);
        const unsigned fmdhi = (unsigned)(recd >> 32);  // fl|ml of d
        if (!nobrk) {
          const int mld = (int)(fmdhi >> 16);
          if (mlp + 1 == mld) {
            flj = d;
          } else {
            bb = u++;  // clone of d with length mlp+1
            // patch phase2 prefix-store effect on tk[d] (d may be pre-t2 node)
            const u64m pb = __ballot(prefl && cid == d);
            if (pb != 0ull) { if (ks) dtr1 = j; else dtr0 = j; }
            if (lane == 0) {
              // rl[bb] copy elided: bb is slot 1 of new chain -> stamped i
              reca[bb] = (u64m)(unsigned short)dtr0
                       | ((u64m)(unsigned short)dtr1 << 16)
                       | ((u64m)(fmdhi & 0xFFFFu) << 32)
                       | ((u64m)(unsigned)(mlp + 1) << 48);
            }
            flj = bb;
          }
        }
        if (lane == 0)
          rech[2 * j + 1] = (unsigned)(flj & 0xFFFF) | ((unsigned)mlj << 16);

        if (bb >= 0) {  // redirect run: contiguous img==d from t2
          const u64m eq = __ballot(cval && img == d) >> t2;
          const int runlen = (eq == ~0ull) ? 64 : (int)__builtin_ctzll(~eq);
          inrun = cval && lane >= t2 && lane < t2 + runlen;
        }
      }
    } else {
      // ================= PHASE 1 — QUERY (reads only; sees post-(i-1)) ====
      const int qs = sym;
      int p, x;
      u64m recP; int rlv;

      // speculative first hop: verify load + spec hop-2 loads issued together
      const u64m fresh = reca[w];            // authoritative reca[w]
      const int tvs = f_tr(rrP, qs);         // spec transition from cached rec
      const int ps = (tvs != -1) ? tvs : 0;
      const u64m rr2 = reca[ps];             // spec hop-2 record
      const int rl2 = (int)(short)rla[ps];   // spec hop-2 rla
      if (fresh == rrP && tvs != -1) {
        // spec hit: both hops resolved with one round of latency
        p = tvs; x = h + 1; recP = rr2; rlv = rl2;
      } else {
        // generic walk1 from the fresh (authoritative) record
        u64m rr = fresh; p = w; x = h;
        for (;;) {
          const int tv = f_tr(rr, qs);
          if (tv != -1) { p = tv; x = x + 1; break; }
          const int mp = f_ml(rr);
          if (x > mp) x = mp;
          p = f_fl(rr);
          if (p == -1) { p = 0; x = 0; break; }
          rr = reca[p];   // ONE b64 per hop
        }
        recP = reca[p]; rlv = (int)(short)rla[p];
      }

      unsigned fmv = (unsigned)(recP >> 32);
      int vst = p;
      for (;;) {
        const int fv = (int)(short)(fmv & 0xFFFFu);
        if (fv == -1) break;
        const unsigned fmf = rech[2 * fv + 1];
        const int rlf = (int)(short)rla[fv];   // speculative, same hop
        if ((int)(fmf >> 16) < x) break;
        vst = fv; fmv = fmf; rlv = rlf;
      }
      int rv = -1;
      for (;;) {
        if (vst == -1) { rv = -1; break; }
        if ((int)(fmv >> 16) > 0 && rlv >= 0) { rv = rlv; break; }
        vst = (int)(short)(fmv & 0xFFFFu);
        if (vst == -1) { rv = -1; break; }
        fmv = rech[2 * vst + 1];
        rlv = (int)(short)rla[vst];
      }
      w = p; h = x;
      rrP = recP;   // cache reca[p] for the next query's speculation
      if (lane == 0) outr[(size_t)i * C] = (unsigned)(rv + 1);
    }

    asm volatile("" ::: "memory");
    __builtin_amdgcn_s_barrier();   // ---- A: query reads done ----
    asm volatile("" ::: "memory");

    if (wid == 0) {
      // ============ PHASE 2 — KEY visible stores (exclusive) ==============
      const int ks = sym;
      if (hot) {
        if (prefl) recw[4 * cid + ks] = (unsigned short)j;
        if (inrun) recw[4 * cid + ks] = (unsigned short)bb;
        if (bb >= 0 && lane == 0) recw[4 * d + 2] = (unsigned short)bb; // fl[d]=bb

        // new chain: [j, flj, run-start images #1.., root]
        int nv = 0;  // default root/padding (safe gather next step)
        if (lane == 0) nv = j;
        else if (lane == 1) nv = flj;
        else if (lane - 1 < ndd) nv = pushed;
        const bool nval = (lane < newlen);
        if (nval) rla[nv] = (unsigned short)i;

        const bool overflow = (newlen > 64);
        if (overflow) {  // cold: stamp the unstored tail serially
          const int nv63 = __builtin_amdgcn_readlane(nv, 63);
          if (lane == 0) {
            int vp = (int)(short)(rech[2 * nv63 + 1] & 0xFFFFu);
            while (vp != -1) {
              rla[vp] = (unsigned short)i;
              vp = (int)(short)(rech[2 * vp + 1] & 0xFFFFu);
            }
          }
        }
        cid = nv; cval = nval; trunc = overflow;
      } else {
        // ===== COLD fallback: reference-exact serial step (R10-verified) ==
        int pcur = g, d2 = -1, idbrk = -1;
        for (;;) {
          if (pcur == -1) break;
          const u64m rr = reca[pcur];
          const int tv = f_tr(rr, ks);
          if (tv != -1) { d2 = tv; idbrk = pcur; break; }
          if (lane == 0) recw[4 * pcur + ks] = (unsigned short)j;
          pcur = f_fl(rr);
        }
        int fl2 = 0;
        if (d2 != -1) {
          const int mlp2 = f_ml(reca[idbrk]);
          const u64m rd2 = reca[d2];
          const int mld = f_ml(rd2);
          if (mlp2 + 1 == mld) {
            fl2 = d2;
          } else {
            const int bbc = u++;
            const int drl = (int)(short)rla[d2];
            if (lane == 0) {
              reca[bbc] = (u64m)(unsigned short)f_tr(rd2, 0)
                        | ((u64m)(unsigned short)f_tr(rd2, 1) << 16)
                        | ((u64m)((unsigned)(rd2 >> 32) & 0xFFFFu) << 32)
                        | ((u64m)(unsigned)(mlp2 + 1) << 48);
              rla[bbc] = (unsigned short)drl;
              recw[4 * d2 + 2] = (unsigned short)bbc;   // fl[d2] = bbc
            }
            fl2 = bbc;
            int p3 = idbrk;
            for (;;) {
              if (p3 == -1) break;
              const u64m r3 = reca[p3];
              const int tv3 = f_tr(r3, ks);
              if (tv3 != d2) break;
              if (lane == 0) recw[4 * p3 + ks] = (unsigned short)bbc;
              p3 = f_fl(r3);
            }
          }
        }
        if (lane == 0)
          rech[2 * j + 1] = (unsigned)(fl2 & 0xFFFF) | ((unsigned)mlj << 16);
        // full propagation walk; rebuild lane chain while stamping
        int vp = j, ncs = 0;
        bool tr2 = false;
        for (;;) {
          if (vp == -1) break;
          if (ncs < 64) { if (lane == ncs) cid = vp; ++ncs; }
          else tr2 = true;
          if (lane == 0) rla[vp] = (unsigned short)i;
          vp = (int)(short)(rech[2 * vp + 1] & 0xFFFFu);
        }
        cval = (lane < ncs);
        trunc = tr2;
      }
      g = j; mlg = mlj;
    }
    // wave1: nothing in phase2.

    // next-step symbol (both waves, own stream)
    if (i + 1 < T) {
      const int in = i + 1;
      const unsigned bw = (unsigned)__builtin_amdgcn_readlane((int)bits, in >> 5);
      sym = (int)((bw >> (in & 31)) & 1u);
    }

    // drain wave0's LDS stores so wave1's next-phase1 reads see them; raw
    // barrier (no vmcnt drain: wave1's outr store stays in flight).
    asm volatile("s_waitcnt lgkmcnt(0)" ::: "memory");
    if (wid == 0 && i + 1 < T) {
      // gather prefetch: issued post-drain (same-wave in-order DS => sees
      // every step-i store; cid final). Issue-only; latency hides under
      // barrier B + wave1's next query start.
      pf_rec = reca[cid];
    }
    __builtin_amdgcn_s_barrier();   // ---- B: automaton post-i published ----
    asm volatile("" ::: "memory");
  }
}

// Fully parallel epilogue: vidx (u32, = r+1, 0 = no match) -> sign*e.
__global__ __launch_bounds__(256)
void samx_epilogue(const float* __restrict__ v,
                   const float* __restrict__ e,
                   unsigned* __restrict__ out,
                   int T, int C, int total) {
  const int idx = blockIdx.x * 256 + threadIdx.x;
  if (idx >= total) return;
  const unsigned vidx = out[idx];
  const int c = idx % C;
  const int bi = idx / C;
  const int b = bi / T;
  const float ev = e[c];
  float val = -ev;  // y=0
  if (vidx != 0u) {
    if (v[((size_t)b * (size_t)T + (size_t)vidx) * (size_t)C + (size_t)c] > 0.0f)
      val = ev;
  }
  out[idx] = __float_as_uint(val);
}

extern "C" void kernel_launch(void* const* d_in, const int* in_sizes, int n_in,
                              void* d_out, int out_size, void* d_ws, size_t ws_size,
                              hipStream_t stream) {
  const float* q = (const float*)d_in[0];
  const float* k = (const float*)d_in[1];
  const float* v = (const float*)d_in[2];
  const float* e = (const float*)d_in[3];

  const int C = in_sizes[3];
  const int T = TLEN;
  const int B = in_sizes[0] / (T * C);
  const int total = out_size;

  samx_main<<<dim3(B * C), dim3(128), 0, stream>>>(q, k, (unsigned*)d_out, T, C);
  samx_epilogue<<<dim3((total + 255) / 256), dim3(256), 0, stream>>>(
      v, e, (unsigned*)d_out, T, C, total);
}